// Round 4
// baseline (403.290 us; speedup 1.0000x reference)
//
#include <hip/hip_runtime.h>

typedef __bf16 bf16;
typedef __attribute__((ext_vector_type(8))) __bf16 bf16x8;
typedef __attribute__((ext_vector_type(4))) __bf16 bf16x4;
typedef __attribute__((ext_vector_type(2))) __bf16 bf16x2;
typedef __attribute__((ext_vector_type(4))) float f32x4;

#define DEVINL __device__ __forceinline__

// Async global->LDS, 16B per lane.
DEVINL void gload_lds16(const bf16* g, bf16* l) {
    __builtin_amdgcn_global_load_lds(
        (__attribute__((address_space(1))) unsigned int*)(unsigned long long)g,
        (__attribute__((address_space(3))) unsigned int*)l,
        16, 0, 0);
}

// XCD-aware swizzle (uniform work): contiguous by-slab per XCD, bx fastest.
// Requires gridDim.y % 8 == 0.
DEVINL void xcd_swizzle(int& bx, int& by) {
    const int gx = gridDim.x, gy = gridDim.y;
    const int l = blockIdx.y * gx + blockIdx.x;
    const int xcd = l & 7;
    const int li = l >> 3;
    by = xcd * (gy >> 3) + li / gx;
    bx = li - (li / gx) * gx;
}

// Balanced XCD swizzle for causal grids (work ∝ by+1), gridDim.y==16 only:
// XCD x owns by = x and by = 15-x  ->  equal live work per XCD.
DEVINL void xcd_swizzle_bal(int& bx, int& by) {
    const int gx = gridDim.x, gy = gridDim.y;
    const int l = blockIdx.y * gx + blockIdx.x;
    const int xcd = l & 7;
    const int li = l >> 3;
    const int j = li / gx;            // slab 0 or 1
    bx = li - j * gx;
    by = j ? (gy - 1 - xcd) : xcd;
}

// ---------------------------------------------------------------- converts
__global__ __launch_bounds__(256) void cvt3_f32_to_bf16(
    const float* __restrict__ a, const float* __restrict__ b,
    const float* __restrict__ c, bf16* __restrict__ out, int n4) {
    int i = blockIdx.x * blockDim.x + threadIdx.x;
    if (i >= n4) return;
    const float* src = (blockIdx.z == 0) ? a : (blockIdx.z == 1) ? b : c;
    bf16* dst = out + (size_t)blockIdx.z * (size_t)n4 * 4;
    float4 f = ((const float4*)src)[i];
    bf16x4 o;
    o.x = (bf16)f.x; o.y = (bf16)f.y; o.z = (bf16)f.z; o.w = (bf16)f.w;
    ((bf16x4*)dst)[i] = o;
}

__global__ __launch_bounds__(256) void cvt4_f32_to_bf16(
    const float* __restrict__ a, const float* __restrict__ b,
    const float* __restrict__ c, const float* __restrict__ d,
    bf16* __restrict__ out, int n4) {
    int i = blockIdx.x * blockDim.x + threadIdx.x;
    if (i >= n4) return;
    const float* src = (blockIdx.z == 0) ? a : (blockIdx.z == 1) ? b
                     : (blockIdx.z == 2) ? c : d;
    bf16* dst = out + (size_t)blockIdx.z * (size_t)n4 * 4;
    float4 f = ((const float4*)src)[i];
    bf16x4 o;
    o.x = (bf16)f.x; o.y = (bf16)f.y; o.z = (bf16)f.z; o.w = (bf16)f.w;
    ((bf16x4*)dst)[i] = o;
}

// ---------------------------------------------------------------- transpose
// ushort4 global access (G13); LDS staging 64x65 as before.
__global__ __launch_bounds__(256) void transpose_bf16(
    const unsigned short* __restrict__ in, unsigned short* __restrict__ out,
    int R, int C) {
    __shared__ unsigned short t[64][65];
    const size_t bo = (size_t)blockIdx.z * R * C;
    const int r0 = blockIdx.y * 64, c0 = blockIdx.x * 64;
    const int tr = threadIdx.x >> 4;      // 0..15
    const int tc = threadIdx.x & 15;      // 0..15
#pragma unroll
    for (int i = 0; i < 4; i++) {
        int r = tr + i * 16;
        ushort4 v = *(const ushort4*)&in[bo + (size_t)(r0 + r) * C + (c0 + tc * 4)];
        t[r][tc * 4 + 0] = v.x; t[r][tc * 4 + 1] = v.y;
        t[r][tc * 4 + 2] = v.z; t[r][tc * 4 + 3] = v.w;
    }
    __syncthreads();
#pragma unroll
    for (int i = 0; i < 4; i++) {
        int r = tr + i * 16;              // output row = original col
        ushort4 v;
        v.x = t[tc * 4 + 0][r]; v.y = t[tc * 4 + 1][r];
        v.z = t[tc * 4 + 2][r]; v.w = t[tc * 4 + 3][r];
        *(ushort4*)&out[bo + (size_t)(c0 + r) * R + (r0 + tc * 4)] = v;
    }
}

// ---------------------------------------------------------------- bias fold
// bout[e] = dot(Wo[e,:], bv) + bo[e]   (one wave per e)
__global__ __launch_bounds__(256) void bias_fold(
    const float* __restrict__ Wo, const float* __restrict__ bv,
    const float* __restrict__ bo, float* __restrict__ bout) {
    const int e = blockIdx.x * 4 + (threadIdx.x >> 6);
    const int lane = threadIdx.x & 63;
    float s = 0.f;
    for (int k = lane; k < 1024; k += 64) s += Wo[e * 1024 + k] * bv[k];
#pragma unroll
    for (int off = 32; off > 0; off >>= 1) s += __shfl_xor(s, off, 64);
    if (lane == 0) bout[e] = s + bo[e];
}

// ------------------------------- GEMM 128x128, BK=32, LDS dbuf + XOR swizzle
// (kept for the small Wvo = Wo @ Wv 1024^3 GEMM only)
template <int EPI>
__global__ __launch_bounds__(256) void gemm_bt128(
    const bf16* __restrict__ A, const bf16* __restrict__ B,
    const float* __restrict__ bias0, const float* __restrict__ bias1,
    const float* __restrict__ bias2, void* __restrict__ Cv,
    int M, int N, int K,
    long long sA, long long sB, long long sC,
    float scale) {
    int bx, by;
    xcd_swizzle(bx, by);
    const int bz = blockIdx.z;
    const int m0 = by * 128, n0 = bx * 128;

    A += (size_t)bz * sA;
    B += (size_t)bz * sB;
    const float* bias = (bz == 0) ? bias0 : (bz == 1) ? bias1 : bias2;

    __shared__ __align__(16) bf16 As[2][128 * 32];
    __shared__ __align__(16) bf16 Bs[2][128 * 32];

    const int tid = threadIdx.x;
    const int wave = tid >> 6;
    const int lane = tid & 63;
    const int lr = lane & 15;
    const int lq = lane >> 4;
    const int wm = (wave >> 1) * 64;
    const int wn = (wave & 1) * 64;
    const int srow = lane >> 2;
    const int scol = ((lane & 3) ^ ((lane >> 3) & 3)) * 8;

    const bf16* gA = A + (size_t)(m0 + wave * 16 + srow) * K + scol;
    const bf16* gB = B + (size_t)(n0 + wave * 16 + srow) * K + scol;
    const size_t rowskip = (size_t)64 * K;
    const int rsw = (lq ^ ((lr >> 1) & 3)) * 8;

    f32x4 acc[4][4];
    const f32x4 fzero = {0.f, 0.f, 0.f, 0.f};
#pragma unroll
    for (int i = 0; i < 4; i++)
#pragma unroll
        for (int j = 0; j < 4; j++) acc[i][j] = fzero;

#define STAGE128(bufi)                                          \
    do {                                                        \
        gload_lds16(gA,           As[bufi] + wave * 512);       \
        gload_lds16(gA + rowskip, As[bufi] + (wave + 4) * 512); \
        gload_lds16(gB,           Bs[bufi] + wave * 512);       \
        gload_lds16(gB + rowskip, Bs[bufi] + (wave + 4) * 512); \
        gA += 32; gB += 32;                                     \
    } while (0)

    STAGE128(0);
    int cur = 0;
    for (int k0 = 0; k0 < K; k0 += 32) {
        __syncthreads();
        if (k0 + 32 < K) STAGE128(cur ^ 1);

        bf16x8 af[4], bfr[4];
#pragma unroll
        for (int i = 0; i < 4; i++)
            af[i] = *(const bf16x8*)(As[cur] + (wm + i * 16 + lr) * 32 + rsw);
#pragma unroll
        for (int j = 0; j < 4; j++)
            bfr[j] = *(const bf16x8*)(Bs[cur] + (wn + j * 16 + lr) * 32 + rsw);
#pragma unroll
        for (int i = 0; i < 4; i++)
#pragma unroll
            for (int j = 0; j < 4; j++)
                acc[i][j] = __builtin_amdgcn_mfma_f32_16x16x32_bf16(
                    af[i], bfr[j], acc[i][j], 0, 0, 0);
        cur ^= 1;
    }
#undef STAGE128

#pragma unroll
    for (int j = 0; j < 4; j++) {
        const int col = n0 + wn + j * 16 + lr;
        const float bb = bias ? bias[col] : 0.0f;
#pragma unroll
        for (int i = 0; i < 4; i++) {
            const int rowb = m0 + wm + i * 16 + lq * 4;
#pragma unroll
            for (int r = 0; r < 4; r++) {
                if (EPI == 0)
                    ((bf16*)Cv)[(size_t)bz * sC + (size_t)(rowb + r) * N + col] =
                        (bf16)(acc[i][j][r] * scale + bb);
                else
                    ((float*)Cv)[(size_t)bz * sC + (size_t)(rowb + r) * N + col] =
                        acc[i][j][r] * scale + bb;
            }
        }
    }
}

// ---------------- GEMM 256x256, BK=64, 512 thr, m201-style 8-phase pipeline
// Per-wave output 128x64 (2M x 4N waves). 2 LDS K-tile buffers (128 KiB).
// Iteration j processes tiles u=2j (buf0), v=2j+1 (buf1); 8 phases, each:
//   { ds_reads for one MFMA quadrant ; stage one half-tile ; [vmcnt] ;
//     barrier ; setprio(1) 16xMFMA setprio(0) ; barrier }
// Staging order: ph1,2 = A(v) h0,h1 ; ph3,4 = B(u+2) h0,h1 ;
//                ph5,6 = A(u+2) h0,h1 ; ph7,8 = B(u+3) h0,h1.
// WAR: each stage lands >=2 barriers after the last ds_read of its region.
// Residency: vmcnt(4) at ph4-end (A(v) landed, B/A(u+2) in flight) and
// ph8-end (tile u+2 landed, B(u+3) in flight). Queue never drains to 0
// in steady state (T4). LDS swizzle: 16B k-granule g stored at slot
// g ^ (row&7); read offsets apply same XOR -> 2-way max bank aliasing.
template <int EPI>
__global__ __launch_bounds__(512) void gemm8p(
    const bf16* __restrict__ A, const bf16* __restrict__ B,
    const float* __restrict__ bias0, const float* __restrict__ bias1,
    const float* __restrict__ bias2, void* __restrict__ Cv,
    int M, int N, int K,
    long long sA, long long sB, long long sC,
    float scale, int causal) {
    int bx, by;
    if (causal) { bx = blockIdx.x; by = blockIdx.y; }
    else        xcd_swizzle(bx, by);
    const int bz = blockIdx.z;
    const int m0 = by * 256, n0 = bx * 256;
    if (causal == 1 && n0 > m0 + 255) return;   // fully above diagonal

    A += (size_t)bz * sA;
    B += (size_t)bz * sB;
    const float* bias = (bz == 0) ? bias0 : (bz == 1) ? bias1 : bias2;

    __shared__ __align__(16) bf16 As[2][256 * 64];
    __shared__ __align__(16) bf16 Bs[2][256 * 64];

    const int tid = threadIdx.x;
    const int w  = tid >> 6;              // 0..7
    const int l  = tid & 63;
    const int lr = l & 15;
    const int lq = l >> 4;                // 0..3
    const int wm = w >> 2;                // 0..1  (M half)
    const int wn = w & 3;                 // 0..3  (N quarter)

    // fragment-read geometry (bf16 units). row&7 == lr&7 for all frag rows.
    const int x  = lr & 7;
    const int c0 = ((lq ^ x)) * 8;        // ks=0 swizzled k-offset
    const int c1 = (((4 | lq) ^ x)) * 8;  // ks=1
    const int aBase = (wm * 128 + lr) * 64;
    const int bBase = (wn * 64 + lr) * 64;

    // staging: wave w, instr t covers rows t*64 + w*8 + l/8 of a 128-row half;
    // source k-granule pre-swizzled so linear LDS dest == swizzled layout.
    const int srow = w * 8 + (l >> 3);
    const int scol = ((l & 7) ^ (l >> 3)) * 8;
    const bf16* gA = A + (size_t)(m0 + srow) * K + scol;
    const bf16* gB = B + (size_t)(n0 + srow) * K + scol;

    f32x4 acc[8][4];
    const f32x4 fz = {0.f, 0.f, 0.f, 0.f};
#pragma unroll
    for (int i = 0; i < 8; i++)
#pragma unroll
        for (int jj = 0; jj < 4; jj++) acc[i][jj] = fz;

    bf16x8 a[8];    // current A quadrant: 4 m-frags x 2 k-slices
    bf16x8 bb[8];   // full B band: 4 n-frags x 2 k-slices

#define ST_A(b, h, kt)                                                         \
    do {                                                                       \
        const bf16* s_ = gA + (size_t)((h) * 128) * K + (size_t)(kt) * 64;     \
        gload_lds16(s_,                  As[b] + (h) * 8192 + w * 512);        \
        gload_lds16(s_ + (size_t)64 * K, As[b] + (h) * 8192 + 4096 + w * 512); \
    } while (0)
#define ST_B(b, h, kt)                                                         \
    do {                                                                       \
        const bf16* s_ = gB + (size_t)((h) * 128) * K + (size_t)(kt) * 64;     \
        gload_lds16(s_,                  Bs[b] + (h) * 8192 + w * 512);        \
        gload_lds16(s_ + (size_t)64 * K, Bs[b] + (h) * 8192 + 4096 + w * 512); \
    } while (0)
#define RD_A(b, q)                                                             \
    {                                                                          \
        _Pragma("unroll")                                                      \
        for (int f = 0; f < 4; ++f) {                                          \
            a[f * 2 + 0] = *(const bf16x8*)(As[b] + aBase + ((q) * 64 + f * 16) * 64 + c0); \
            a[f * 2 + 1] = *(const bf16x8*)(As[b] + aBase + ((q) * 64 + f * 16) * 64 + c1); \
        }                                                                      \
    }
#define RD_B(b, p)                                                             \
    {                                                                          \
        _Pragma("unroll")                                                      \
        for (int n = 0; n < 2; ++n) {                                          \
            bb[((p) * 2 + n) * 2 + 0] = *(const bf16x8*)(Bs[b] + bBase + ((p) * 32 + n * 16) * 64 + c0); \
            bb[((p) * 2 + n) * 2 + 1] = *(const bf16x8*)(Bs[b] + bBase + ((p) * 32 + n * 16) * 64 + c1); \
        }                                                                      \
    }
#define MM(q, p)                                                               \
    {                                                                          \
        __builtin_amdgcn_s_setprio(1);                                         \
        _Pragma("unroll")                                                      \
        for (int f = 0; f < 4; ++f) {                                          \
            _Pragma("unroll")                                                  \
            for (int n = 0; n < 2; ++n) {                                      \
                acc[(q) * 4 + f][(p) * 2 + n] = __builtin_amdgcn_mfma_f32_16x16x32_bf16( \
                    a[f * 2 + 0], bb[((p) * 2 + n) * 2 + 0], acc[(q) * 4 + f][(p) * 2 + n], 0, 0, 0); \
                acc[(q) * 4 + f][(p) * 2 + n] = __builtin_amdgcn_mfma_f32_16x16x32_bf16( \
                    a[f * 2 + 1], bb[((p) * 2 + n) * 2 + 1], acc[(q) * 4 + f][(p) * 2 + n], 0, 0, 0); \
            }                                                                  \
        }                                                                      \
        __builtin_amdgcn_s_setprio(0);                                         \
    }
#define BAR()                                                                  \
    {                                                                          \
        __builtin_amdgcn_sched_barrier(0);                                     \
        __builtin_amdgcn_s_barrier();                                          \
        __builtin_amdgcn_sched_barrier(0);                                     \
    }

    const int NTt = K >> 6;    // 64-wide K-tiles (even, >=2)
    const int NI  = NTt >> 1;

    // prologue: tile0 fully + B-halves of tile1; tile0 resident after wait.
    ST_B(0, 0, 0); ST_B(0, 1, 0);
    ST_A(0, 0, 0); ST_A(0, 1, 0);
    ST_B(1, 0, 1); ST_B(1, 1, 1);
    asm volatile("s_waitcnt vmcnt(4)" ::: "memory");
    BAR();

    for (int j = 0; j < NI; ++j) {
        const int vkt = 2 * j + 1, ckt = 2 * j + 2, dkt = 2 * j + 3;
        const bool dc = ckt < NTt, dd = dkt < NTt;

        // ===== tile u = 2j (buf0) =====
        RD_A(0, 0) RD_B(0, 0)                 // ph1
        ST_A(1, 0, vkt);
        BAR() MM(0, 0) BAR()
        RD_B(0, 1)                            // ph2
        ST_A(1, 1, vkt);
        BAR() MM(0, 1) BAR()
        RD_A(0, 1)                            // ph3
        if (dc) ST_B(0, 0, ckt);
        BAR() MM(1, 1) BAR()
        if (dc) {                             // ph4
            ST_B(0, 1, ckt);
            asm volatile("s_waitcnt vmcnt(4)" ::: "memory");
        } else {
            asm volatile("s_waitcnt vmcnt(0)" ::: "memory");
        }
        BAR() MM(1, 0) BAR()

        // ===== tile v = 2j+1 (buf1) =====
        RD_A(1, 0) RD_B(1, 0)                 // ph5
        if (dc) ST_A(0, 0, ckt);
        BAR() MM(0, 0) BAR()
        RD_B(1, 1)                            // ph6
        if (dc) ST_A(0, 1, ckt);
        BAR() MM(0, 1) BAR()
        RD_A(1, 1)                            // ph7
        if (dd) ST_B(1, 0, dkt);
        BAR() MM(1, 1) BAR()
        if (dd) ST_B(1, 1, dkt);              // ph8
        if (j + 1 < NI) {
            if (dd) asm volatile("s_waitcnt vmcnt(4)" ::: "memory");
            else    asm volatile("s_waitcnt vmcnt(0)" ::: "memory");
        }
        BAR() MM(1, 0) BAR()
    }
#undef ST_A
#undef ST_B
#undef RD_A
#undef RD_B
#undef MM
#undef BAR

#pragma unroll
    for (int p = 0; p < 4; ++p) {
        const int col = n0 + wn * 64 + p * 16 + lr;
        const float bbv = bias ? bias[col] : 0.0f;
#pragma unroll
        for (int f = 0; f < 8; ++f) {
            const int rowb = m0 + wm * 128 + f * 16 + lq * 4;
#pragma unroll
            for (int r = 0; r < 4; ++r) {
                if (EPI == 0)
                    ((bf16*)Cv)[(size_t)bz * sC + (size_t)(rowb + r) * N + col] =
                        (bf16)(acc[f][p][r] * scale + bbv);
                else
                    ((float*)Cv)[(size_t)bz * sC + (size_t)(rowb + r) * N + col] =
                        acc[f][p][r] * scale + bbv;
            }
        }
    }
}

// ---------------- GEMM 128x128, BK=32, 256 thr, 4-buf template-phase pipe
// 64 KiB LDS -> 2 blocks/CU so causal K-trimmed blocks pair on a CU.
// PV: Keff = m0+128; balanced pair swizzle -> uniform total K per XCD.
__global__ __launch_bounds__(256, 2) void gemm_pv128(
    const bf16* __restrict__ A, const bf16* __restrict__ B,
    const float* __restrict__ bias, float* __restrict__ C,
    int M, int N, int K,
    long long sA, long long sB, long long sC,
    float scale) {
    int bx, by;
    xcd_swizzle_bal(bx, by);
    const int bz = blockIdx.z;
    const int m0 = by * 128, n0 = bx * 128;
    int Keff = m0 + 128; if (Keff > K) Keff = K;
    const int NT = Keff >> 5;   // >= 4

    A += (size_t)bz * sA;
    B += (size_t)bz * sB;

    __shared__ __align__(16) bf16 As[4][128 * 32];
    __shared__ __align__(16) bf16 Bs[4][128 * 32];

    const int tid = threadIdx.x;
    const int wave = tid >> 6;            // 0..3
    const int lane = tid & 63;
    const int lr = lane & 15;
    const int lq = lane >> 4;
    const int wm = (wave >> 1) * 64;
    const int wn = (wave & 1) * 64;

    const int srow = lane >> 2;
    const int scol = ((lane & 3) ^ ((lane >> 3) & 3)) * 8;
    const bf16* gA = A + (size_t)(m0 + wave * 16 + srow) * K + scol;
    const bf16* gB = B + (size_t)(n0 + wave * 16 + srow) * K + scol;
    const size_t rowskip = (size_t)64 * K;

    const int rsw = (lq ^ ((lr >> 1) & 3)) * 8;

    f32x4 acc[4][4];
    const f32x4 fzero = {0.f, 0.f, 0.f, 0.f};
#pragma unroll
    for (int i = 0; i < 4; i++)
#pragma unroll
        for (int j = 0; j < 4; j++) acc[i][j] = fzero;

#define STAGEV(bufi, koff)                                                 \
    do {                                                                   \
        gload_lds16(gA + (koff),           As[bufi] + wave * 512);         \
        gload_lds16(gA + rowskip + (koff), As[bufi] + (wave + 4) * 512);   \
        gload_lds16(gB + (koff),           Bs[bufi] + wave * 512);         \
        gload_lds16(gB + rowskip + (koff), Bs[bufi] + (wave + 4) * 512);   \
    } while (0)

    STAGEV(0, 0);
    STAGEV(1, 32);
    STAGEV(2, 64);
    asm volatile("s_waitcnt vmcnt(8)" ::: "memory");
    __builtin_amdgcn_s_barrier();

    for (int t = 0; t < NT; ++t) {
        const int bfi = t & 3;

        bf16x8 af[4], bfr[4];
#pragma unroll
        for (int i = 0; i < 4; i++)
            af[i] = *(const bf16x8*)(As[bfi] + (wm + i * 16 + lr) * 32 + rsw);
#pragma unroll
        for (int j = 0; j < 4; j++)
            bfr[j] = *(const bf16x8*)(Bs[bfi] + (wn + j * 16 + lr) * 32 + rsw);

        if (t + 3 < NT) STAGEV((t + 3) & 3, (t + 3) * 32);

        const int rem = NT - 1 - t;
        if (rem >= 3)      asm volatile("s_waitcnt vmcnt(8)" ::: "memory");
        else if (rem == 2) asm volatile("s_waitcnt vmcnt(4)" ::: "memory");
        else if (rem == 1) asm volatile("s_waitcnt vmcnt(0)" ::: "memory");
        __builtin_amdgcn_s_barrier();
        __builtin_amdgcn_sched_barrier(0);

        __builtin_amdgcn_s_setprio(1);
#pragma unroll
        for (int i = 0; i < 4; i++)
#pragma unroll
            for (int j = 0; j < 4; j++)
                acc[i][j] = __builtin_amdgcn_mfma_f32_16x16x32_bf16(
                    af[i], bfr[j], acc[i][j], 0, 0, 0);
        __builtin_amdgcn_s_setprio(0);
        __builtin_amdgcn_s_barrier();
    }
#undef STAGEV

#pragma unroll
    for (int j = 0; j < 4; j++) {
        const int col = n0 + wn + j * 16 + lr;
        const float bb = bias[col];
#pragma unroll
        for (int i = 0; i < 4; i++) {
            const int rowb = m0 + wm + i * 16 + lq * 4;
#pragma unroll
            for (int r = 0; r < 4; r++)
                C[(size_t)bz * sC + (size_t)(rowb + r) * N + col] =
                    acc[i][j][r] * scale + bb;
        }
    }
}

// ---------------------------------------------------------------- softmax
__global__ __launch_bounds__(256) void softmax_causal(
    const bf16* __restrict__ Sc, bf16* __restrict__ P, int S) {
    const int row = blockIdx.x;          // b*S + q
    const int q = row & (S - 1);
    const bf16* src = Sc + (size_t)row * S;
    bf16* dst = P + (size_t)row * S;
    const int L = q + 1;
    const int tid = threadIdx.x;
    const int k0 = tid * 8;

    bf16x8 u = ((const bf16x8*)src)[tid];
    float v[8];
    float mx = -3.0e38f;
#pragma unroll
    for (int i = 0; i < 8; i++) {
        v[i] = (k0 + i < L) ? (float)u[i] : -3.0e38f;
        mx = fmaxf(mx, v[i]);
    }
#pragma unroll
    for (int off = 32; off > 0; off >>= 1) mx = fmaxf(mx, __shfl_xor(mx, off, 64));
    __shared__ float redm[4], reds[4];
    if ((tid & 63) == 0) redm[tid >> 6] = mx;
    __syncthreads();
    mx = fmaxf(fmaxf(redm[0], redm[1]), fmaxf(redm[2], redm[3]));

    float sum = 0.f;
#pragma unroll
    for (int i = 0; i < 8; i++) {
        float e = (v[i] > -1.0e38f) ? __expf(v[i] - mx) : 0.f;
        v[i] = e;
        sum += e;
    }
#pragma unroll
    for (int off = 32; off > 0; off >>= 1) sum += __shfl_xor(sum, off, 64);
    if ((tid & 63) == 0) reds[tid >> 6] = sum;
    __syncthreads();
    sum = reds[0] + reds[1] + reds[2] + reds[3];
    const float inv = 1.0f / sum;
    bf16x8 o;
#pragma unroll
    for (int i = 0; i < 8; i++) o[i] = (bf16)(v[i] * inv);
    ((bf16x8*)dst)[tid] = o;
}

// ---------------------------------------------------------------- launch
extern "C" void kernel_launch(void* const* d_in, const int* in_sizes, int n_in,
                              void* d_out, int out_size, void* d_ws, size_t ws_size,
                              hipStream_t stream) {
    const int B = 4, S = 2048, E = 1024;
    const size_t SBE = (size_t)B * S * E;   // 8,388,608
    const size_t EE = (size_t)E * E;        // 1,048,576

    const float* q_in = (const float*)d_in[0];
    const float* k_in = (const float*)d_in[1];
    const float* v_in = (const float*)d_in[2];
    // d_in[3] = mask (tril) — causality handled by index math
    const float* Wq = (const float*)d_in[4];
    const float* bq = (const float*)d_in[5];
    const float* Wk = (const float*)d_in[6];
    const float* bk = (const float*)d_in[7];
    const float* Wv = (const float*)d_in[8];
    const float* bv = (const float*)d_in[9];
    const float* Wo = (const float*)d_in[10];
    const float* bo = (const float*)d_in[11];

    char* ws = (char*)d_ws;
    // Region A (67 MB), time-multiplexed:
    //   [0,48M): qkvb (phase 1), then Sc bf16 [0,33.5M) (phase 2)
    //   [48M,50M): WvT (bf16 Wv^T, live during Wvo prep)
    //   [50M,+4KB): bout
    bf16* qkvb = (bf16*)ws;
    bf16* Sc = (bf16*)ws;
    bf16* WvT = (bf16*)(ws + 3 * SBE * 2);
    float* bout = (float*)(ws + 3 * SBE * 2 + EE * 2);
    char* p = ws + (size_t)B * S * S * 4;
    bf16* QKVb = (bf16*)p; p += 3 * SBE * 2;   // Qb|Kb|VW contiguous
    bf16* VWt = (bf16*)p; p += SBE * 2;
    bf16* Pb = (bf16*)p; p += (size_t)B * S * S * 2;
    bf16* Wb = (bf16*)p; p += 4 * EE * 2;      // Wq|Wk|Wv(->Wvo)|Wo

    bf16* Qb = QKVb;
    bf16* Kb = QKVb + SBE;
    bf16* VW = QKVb + 2 * SBE;
    bf16* Wob = Wb + 3 * EE;
    bf16* Wvo = Wb + 2 * EE;   // Wv slot overwritten by Wvo after transpose

    dim3 blk(256), blk512(512);

    // 1. converts
    dim3 gcvt3((int)(SBE / 4 / 256), 1, 3);
    cvt3_f32_to_bf16<<<gcvt3, blk, 0, stream>>>(q_in, k_in, v_in, qkvb, (int)(SBE / 4));
    dim3 gcvt4((int)(EE / 4 / 256), 1, 4);
    cvt4_f32_to_bf16<<<gcvt4, blk, 0, stream>>>(Wq, Wk, Wv, Wo, Wb, (int)(EE / 4));

    // 2. WvT = Wv^T ; Wvo = Wo @ Wv (B^T GEMM with B=WvT) ; bout = Wo bv + bo
    dim3 gtw(16, 16, 1);
    transpose_bf16<<<gtw, blk, 0, stream>>>((const unsigned short*)(Wb + 2 * EE),
                                            (unsigned short*)WvT, E, E);
    dim3 gwvo(E / 128, E / 128, 1);
    gemm_bt128<0><<<gwvo, blk, 0, stream>>>(Wob, WvT, nullptr, nullptr, nullptr,
                                            Wvo, E, E, E, 0, 0, 0, 1.f);
    bias_fold<<<256, blk, 0, stream>>>(Wo, bv, bo, bout);

    // 3. fused projections: z=0 Q (bq), z=1 K (bk), z=2 VW = v_in @ Wvo^T
    dim3 gproj(E / 256, (B * S) / 256, 3);
    gemm8p<0><<<gproj, blk512, 0, stream>>>(qkvb, Wb, bq, bk, nullptr, QKVb,
                                            B * S, E, E,
                                            (long long)SBE, (long long)EE,
                                            (long long)SBE, 1.f, 0);

    // 4. VW^T per batch: [S,E] -> [E,S]
    dim3 gt(E / 64, S / 64, B);
    transpose_bf16<<<gt, blk, 0, stream>>>((const unsigned short*)VW,
                                           (unsigned short*)VWt, S, E);

    // 5. scores = Q K^T / 32 -> bf16; 256^2 causal grid: 144 live blocks
    //    of 256 -> one concurrent round
    dim3 gsc(S / 256, S / 256, B);
    gemm8p<0><<<gsc, blk512, 0, stream>>>(Qb, Kb, nullptr, nullptr, nullptr, Sc,
                                          S, S, E,
                                          (long long)S * E, (long long)S * E,
                                          (long long)S * S, 0.03125f, 1);

    // 6. causal softmax -> bf16 probs (zeros above diagonal)
    softmax_causal<<<B * S, blk, 0, stream>>>(Sc, Pb, S);

    // 7. out = P @ VW + bout, causal K-trim (Keff = m0+128), 2 blocks/CU
    //    (long+short blocks pair on a CU), XCD-pair-balanced.
    dim3 gpv(E / 128, S / 128, B);
    gemm_pv128<<<gpv, blk, 0, stream>>>(Pb, VWt, bout, (float*)d_out, S, E, S,
                                        (long long)S * S, (long long)E * S,
                                        (long long)S * E, 1.f);
}